// Round 17
// baseline (1092.276 us; speedup 1.0000x reference)
//
#include <hip/hip_runtime.h>
#include <math.h>

#define Bn 16
#define Ln 1444      // 38*38
#define NCn 21
#define Cn 64
#define NBn 23       // 64-position tiles
#define KC 1344      // 21*64
#define RA 16        // amplification factor

// ---- Kernel B: R13 version (passing, ~6.3 us) -----------------------------
__global__ __launch_bounds__(256) void kB(const float* __restrict__ cls_pred,
                                          const float* __restrict__ source,
                                          const float* __restrict__ R,
                                          int* __restrict__ cls_idx,
                                          float* __restrict__ src_out,
                                          float* __restrict__ bs,
                                          float2* __restrict__ Gg) {
    int b = blockIdx.x & 15, m = blockIdx.x >> 4;
    int base = m * 64;
    int lane = threadIdx.x & 63, grp = threadIdx.x >> 6;
    __shared__ float sh[9536];
    __shared__ int cls[64];
    float (*tile)[65] = (float(*)[65])sh;
    float* clsP = sh + 4160;
    float* WS   = sh + 4160;

    if (blockIdx.x == 0) {
        for (int i = threadIdx.x; i < 441; i += 256) {
            int a = i / 21, k = i % 21;
            float rak = R[a * 21 + k], rka = R[k * 21 + a];
            Gg[i] = make_float2(rak - rka, rka);
        }
    }
#pragma unroll
    for (int cc = 0; cc < 16; cc++) {
        int c = grp * 16 + cc;
        float v = 0.f;
        if (base + lane < Ln) v = source[((size_t)b * Cn + c) * Ln + base + lane];
        tile[c][lane] = v;
    }
    {
        const float4* gp = reinterpret_cast<const float4*>(cls_pred + ((size_t)b * Ln + base) * 84);
        int lim4 = (Ln - base) * 21;
#pragma unroll
        for (int it = 0; it < 6; it++) {
            int f4 = threadIdx.x + it * 256;
            if (f4 < 1344) {
                float4 v = (f4 < lim4) ? gp[f4] : make_float4(0.f, 0.f, 0.f, 0.f);
                reinterpret_cast<float4*>(clsP)[f4] = v;
            }
        }
    }
    __syncthreads();

    {
        int p = threadIdx.x >> 2, a = threadIdx.x & 3;
        bool valid = (base + p < Ln);
        const float* q = clsP + p * 84 + a * 21;
        float x[21];
#pragma unroll
        for (int i = 0; i < 21; i++) x[i] = q[i];
        float mx = x[0];
#pragma unroll
        for (int i = 1; i < 21; i++) mx = fmaxf(mx, x[i]);
        float s = 0.f;
#pragma unroll
        for (int i = 0; i < 21; i++) { x[i] = expf(x[i] - mx); s += x[i]; }
        float best = -1.f; int bi = 0;
#pragma unroll
        for (int i = 0; i < 21; i++) {
            float sm = x[i] / s;
            if (sm > best) { best = sm; bi = a * 21 + i; }
        }
#pragma unroll
        for (int d = 1; d <= 2; d <<= 1) {
            float ob = __shfl_xor(best, d);
            int oi = __shfl_xor(bi, d);
            if (ob > best || (ob == best && oi < bi)) { best = ob; bi = oi; }
        }
        if (a == 0) {
            if (valid) { int k = bi % 21; cls[p] = k; cls_idx[b * Ln + base + p] = k; }
            else cls[p] = 255;
        }
    }
    __syncthreads();

    float cs[21];
#pragma unroll
    for (int k = 0; k < 21; k++) cs[k] = 0.f;
#pragma unroll
    for (int jj = 0; jj < 16; jj++) {
        int j = grp * 16 + jj;
        float v = tile[lane][j];
        if (base + j < Ln) src_out[((size_t)b * Ln + base + j) * Cn + lane] = v;
        int k = cls[j];
#pragma unroll
        for (int kk = 0; kk < 21; kk++) cs[kk] += (kk == k) ? v : 0.f;
    }
#pragma unroll
    for (int kk = 0; kk < 21; kk++) WS[grp * KC + kk * 64 + lane] = cs[kk];
    __syncthreads();

    for (int i = threadIdx.x; i < KC; i += 256) {
        float v = WS[i] + WS[KC + i] + WS[2 * KC + i] + WS[3 * KC + i];
        bs[((size_t)b * NBn + m) * KC + i] = v;
    }
}

// ---- shared body for the two probe kernels --------------------------------
// AF: amplify {final combine + stores}; AC: amplify {sT reload + cs build}
template<int AF, int AC>
__device__ __forceinline__ void kC_body(const float* __restrict__ src,
                                        const int* __restrict__ cls_idx,
                                        const float2* __restrict__ Gg,
                                        const float* __restrict__ bs,
                                        float* __restrict__ fused) {
    int b = blockIdx.x & 15, m = blockIdx.x >> 4;
    int base = m * 64;
    int lane = threadIdx.x & 63, grp = threadIdx.x >> 6;
    __shared__ float PS[KC];
    __shared__ float Tt[KC];
    __shared__ float WS[8][KC];
    __shared__ int cls[64];

    volatile int zv = 0;
    int z = zv;                      // runtime 0, opaque
    float zf = (float)z;

    float sT[8];
#pragma unroll
    for (int t = 0; t < 8; t++) {
        int i = grp * 8 + t;
        sT[t] = (base + i < Ln) ? src[((size_t)b * Ln + base + i) * Cn + lane] : 0.f;
    }
    if (threadIdx.x < 64) {
        int k = 0;
        if (base + (int)threadIdx.x < Ln) k = cls_idx[b * Ln + base + threadIdx.x];
        cls[threadIdx.x] = k;
    }
    if (threadIdx.x < KC / 4) {
        int g = threadIdx.x;
        float rx = 0.f, ry = 0.f, rz = 0.f, rw = 0.f;
        float px = 0.f, py = 0.f, pz = 0.f, pw = 0.f;
#pragma unroll
        for (int mm = 0; mm < NBn; mm++) {
            float4 v = *reinterpret_cast<const float4*>(&bs[((size_t)b * NBn + mm) * KC + g * 4]);
            rx += v.x; ry += v.y; rz += v.z; rw += v.w;
            if (mm < m) { px += v.x; py += v.y; pz += v.z; pw += v.w; }
        }
        PS[g * 4] = px; PS[g * 4 + 1] = py; PS[g * 4 + 2] = pz; PS[g * 4 + 3] = pw;
        Tt[g * 4] = rx; Tt[g * 4 + 1] = ry; Tt[g * 4 + 2] = rz; Tt[g * 4 + 3] = rw;
    }
    __syncthreads();   // S1

    int cj[8];
#pragma unroll
    for (int j = 0; j < 8; j++) cj[j] = cls[grp * 8 + j];

    // cs build (amplified AC; zf*rep defeats CSE; per-rep sink keeps it live)
    float cs[21];
#pragma unroll 1
    for (int rep = 0; rep < AC; rep++) {
        float sTr[8];
#pragma unroll
        for (int t = 0; t < 8; t++) {
            int i = grp * 8 + t;
            sTr[t] = (base + i < Ln)
                     ? src[((size_t)b * Ln + base + i) * Cn + lane + (size_t)(z * rep)]
                     : 0.f;
            sTr[t] += zf * (float)rep;
        }
#pragma unroll
        for (int k = 0; k < 21; k++) cs[k] = 0.f;
#pragma unroll
        for (int t = 0; t < 8; t++) {
            int k = cj[t];
#pragma unroll
            for (int kk = 0; kk < 21; kk++) cs[kk] += (kk == k) ? sTr[t] : 0.f;
        }
        float snk = 0.f;
#pragma unroll
        for (int k = 0; k < 21; k++) snk += cs[k];
        asm volatile("" :: "v"(snk));
    }
#pragma unroll
    for (int kk = 0; kk < 21; kk++) WS[grp][kk * 64 + lane] = cs[kk];
    __syncthreads();   // S2

    for (int i = threadIdx.x; i < KC; i += 512) {
        float run = PS[i];
#pragma unroll
        for (int g = 0; g < 8; g++) {
            float w = WS[g][i];
            WS[g][i] = run;
            run += w;
        }
    }
    __syncthreads();   // S3

    float Tc[21], msW[21];
#pragma unroll
    for (int k = 0; k < 21; k++) Tc[k] = Tt[k * 64 + lane];
#pragma unroll
    for (int k = 0; k < 21; k++) msW[k] = WS[grp][k * 64 + lane];

    // final combine (amplified AF; rep-dependent Gg base defeats s_load CSE)
    int nvalid = (Ln - base < 64) ? (Ln - base) : 64;
#pragma unroll 1
    for (int rep = 0; rep < AF; rep++) {
        const float2* GgR = Gg + (size_t)(z * rep);
#pragma unroll
        for (int t = 0; t < 8; t++) {
            int i = grp * 8 + t;
            if (i < nvalid) {
                int cis = __builtin_amdgcn_readfirstlane(cj[t]);
                const float2* grow = GgR + cis * 21;
                float sv = sT[t];
                float accA = (((cis != 0) ? 1.f : 0.f) - grow[cis].y) * sv;
                float accB = 0.f;
#pragma unroll
                for (int k = 0; k < 21; k++) {
                    float2 w = grow[k];
                    accA = fmaf(w.x, msW[k], accA);
                    accB = fmaf(w.y, Tc[k], accB);
                }
#pragma unroll
                for (int j = 0; j < 8; j++)
                    if (j < t) {
                        int cjs = __builtin_amdgcn_readfirstlane(cj[j]);
                        accA = fmaf(grow[cjs].x, sT[j], accA);
                    }
                fused[((size_t)b * Ln + base + i) * Cn + lane] = accA + accB;
            }
        }
    }
}

// distinct NAMES so rocprof rows are unambiguous (R14 lesson)
__global__ __launch_bounds__(512, 2) void kCfin(const float* __restrict__ src,
                                                const int* __restrict__ cls_idx,
                                                const float2* __restrict__ Gg,
                                                const float* __restrict__ bs,
                                                float* __restrict__ fused) {
    kC_body<RA, 1>(src, cls_idx, Gg, bs, fused);
}
__global__ __launch_bounds__(512, 2) void kCcs(const float* __restrict__ src,
                                               const int* __restrict__ cls_idx,
                                               const float2* __restrict__ Gg,
                                               const float* __restrict__ bs,
                                               float* __restrict__ fused) {
    kC_body<1, RA>(src, cls_idx, Gg, bs, fused);
}

extern "C" void kernel_launch(void* const* d_in, const int* in_sizes, int n_in,
                              void* d_out, int out_size, void* d_ws, size_t ws_size,
                              hipStream_t stream) {
    const float* cls_pred = (const float*)d_in[0];
    const float* source = (const float*)d_in[1];
    const float* cls_r_prob = (const float*)d_in[2];

    float* fused = (float*)d_out;
    float* src_out = fused + (size_t)Bn * Ln * Cn;

    char* w = (char*)d_ws;
    int* cls_idx = (int*)w;
    size_t off = ((size_t)Bn * Ln * 4 + 1023) & ~(size_t)1023;
    float* bs = (float*)(w + off);
    float2* Gg = (float2*)(w + off + (size_t)Bn * NBn * KC * 4);

    hipLaunchKernelGGL(kB, dim3(Bn * NBn), dim3(256), 0, stream,
                       cls_pred, source, cls_r_prob, cls_idx, src_out, bs, Gg);
    hipLaunchKernelGGL(kCfin, dim3(Bn * NBn), dim3(512), 0, stream,
                       src_out, cls_idx, Gg, bs, fused);
    hipLaunchKernelGGL(kCcs, dim3(Bn * NBn), dim3(512), 0, stream,
                       src_out, cls_idx, Gg, bs, fused);
}

// Round 18
// 30.391 us; speedup vs baseline: 35.9414x; 35.9414x over previous
//
#include <hip/hip_runtime.h>
#include <math.h>

#define Bn 16
#define Ln 1444      // 38*38
#define NCn 21
#define Cn 64
#define NBn 23       // 64-position tiles
#define NPAIR 12     // ceil(23/2) tile-pairs per batch
#define KC 1344      // 21*64

// ---- Kernel B: two R13-tiles per block (512 thr = 2 x 256), balanced grid -
// LDS: sh[2][9536] (74.5KB) + cls 512B -> 2 blk/CU capacity; grid 192 -> 1/CU.
__global__ __launch_bounds__(512) void kB(const float* __restrict__ cls_pred,
                                          const float* __restrict__ source,
                                          const float* __restrict__ R,
                                          int* __restrict__ cls_idx,
                                          float* __restrict__ src_out,
                                          float* __restrict__ bs,
                                          float2* __restrict__ Gg) {
    int b = blockIdx.x & 15, q = blockIdx.x >> 4;    // q: 0..11
    int half = threadIdx.x >> 8;                     // 0/1
    int tid = threadIdx.x & 255;
    int m = 2 * q + half;                            // 23 = masked-off tile
    int base = m * 64;
    int lane = tid & 63, grp = tid >> 6;
    __shared__ float sh[2][9536];
    __shared__ int cls[2][64];
    float (*tile)[65] = (float(*)[65])sh[half];
    float* clsP = sh[half] + 4160;                   // dead after classify
    float* WS   = sh[half] + 4160;                   // overlays clsP

    if (blockIdx.x == 0) {
        for (int i = threadIdx.x; i < 441; i += 512) {
            int a = i / 21, k = i % 21;
            float rak = R[a * 21 + k], rka = R[k * 21 + a];
            Gg[i] = make_float2(rak - rka, rka);
        }
    }
#pragma unroll
    for (int cc = 0; cc < 16; cc++) {
        int c = grp * 16 + cc;
        float v = 0.f;
        if (base + lane < Ln) v = source[((size_t)b * Cn + c) * Ln + base + lane];
        tile[c][lane] = v;
    }
    {
        const float4* gp = reinterpret_cast<const float4*>(cls_pred + ((size_t)b * Ln + base) * 84);
        int lim4 = (Ln - base) * 21;                 // negative for m=23
#pragma unroll
        for (int it = 0; it < 6; it++) {
            int f4 = tid + it * 256;
            if (f4 < 1344) {
                float4 v = (f4 < lim4) ? gp[f4] : make_float4(0.f, 0.f, 0.f, 0.f);
                reinterpret_cast<float4*>(clsP)[f4] = v;
            }
        }
    }
    __syncthreads();   // S1

    {
        int p = tid >> 2, a = tid & 3;
        bool valid = (base + p < Ln);
        const float* qq = clsP + p * 84 + a * 21;
        float x[21];
#pragma unroll
        for (int i = 0; i < 21; i++) x[i] = qq[i];
        float mx = x[0];
#pragma unroll
        for (int i = 1; i < 21; i++) mx = fmaxf(mx, x[i]);
        float s = 0.f;
#pragma unroll
        for (int i = 0; i < 21; i++) { x[i] = expf(x[i] - mx); s += x[i]; }
        float best = -1.f; int bi = 0;
#pragma unroll
        for (int i = 0; i < 21; i++) {
            float sm = x[i] / s;                     // exact per-element division (matches ref)
            if (sm > best) { best = sm; bi = a * 21 + i; }
        }
#pragma unroll
        for (int d = 1; d <= 2; d <<= 1) {
            float ob = __shfl_xor(best, d);
            int oi = __shfl_xor(bi, d);
            if (ob > best || (ob == best && oi < bi)) { best = ob; bi = oi; }
        }
        if (a == 0) {
            if (valid) { int k = bi % 21; cls[half][p] = k; cls_idx[b * Ln + base + p] = k; }
            else cls[half][p] = 255;
        }
    }
    __syncthreads();   // S2: cls ready, clsP dead

    float cs[21];
#pragma unroll
    for (int k = 0; k < 21; k++) cs[k] = 0.f;
#pragma unroll
    for (int jj = 0; jj < 16; jj++) {
        int j = grp * 16 + jj;
        float v = tile[lane][j];
        if (base + j < Ln) src_out[((size_t)b * Ln + base + j) * Cn + lane] = v;
        int k = cls[half][j];
#pragma unroll
        for (int kk = 0; kk < 21; kk++) cs[kk] += (kk == k) ? v : 0.f;
    }
#pragma unroll
    for (int kk = 0; kk < 21; kk++) WS[grp * KC + kk * 64 + lane] = cs[kk];
    __syncthreads();   // S3

    if (m < NBn) {
        for (int i = tid; i < KC; i += 256) {
            float v = WS[i] + WS[KC + i] + WS[2 * KC + i] + WS[3 * KC + i];
            bs[((size_t)b * NBn + m) * KC + i] = v;
        }
    }
}

// ---- Kernel C: two tiles per block (1024 thr), shared stream, balanced ----
// LDS: PS[2]+Tt+WS[2][8] = 19*KC*4 = 102144B + cls 512B -> 1 blk/CU; grid 192.
__global__ __launch_bounds__(1024) void kC(const float* __restrict__ src,
                                           const int* __restrict__ cls_idx,
                                           const float2* __restrict__ Gg,
                                           const float* __restrict__ bs,
                                           float* __restrict__ fused) {
    int b = blockIdx.x & 15, q = blockIdx.x >> 4;    // q: 0..11
    int half = threadIdx.x >> 9;                     // 0/1
    int tid = threadIdx.x & 511;
    int m = 2 * q + half;                            // 23 = masked-off tile
    int base = m * 64;
    int lane = tid & 63, grp = tid >> 6;             // 8 waves per half
    __shared__ float PS[2][KC];
    __shared__ float Tt[KC];
    __shared__ float WS[2][8][KC];
    __shared__ int cls[2][64];

    // own 8 positions (masked half loads nothing)
    float sT[8];
#pragma unroll
    for (int t = 0; t < 8; t++) {
        int i = grp * 8 + t;
        sT[t] = (base + i < Ln) ? src[((size_t)b * Ln + base + i) * Cn + lane] : 0.f;
    }
    if (threadIdx.x < 128) {
        int h = threadIdx.x >> 6, p = threadIdx.x & 63;
        int mm = 2 * q + h;
        int k = 0;
        if (mm * 64 + p < Ln) k = cls_idx[b * Ln + mm * 64 + p];
        cls[h][p] = k;
    }
    // shared stream: one pass produces PS_A (mm<2q), PS_B (mm<2q+1), Tt
    if (threadIdx.x < KC / 4) {
        int g = threadIdx.x;
        float rx = 0.f, ry = 0.f, rz = 0.f, rw = 0.f;
        float ax = 0.f, ay = 0.f, az = 0.f, aw = 0.f;
        float bx = 0.f, by = 0.f, bz = 0.f, bw = 0.f;
        int mA = 2 * q, mB = 2 * q + 1;
#pragma unroll
        for (int mm = 0; mm < NBn; mm++) {
            float4 v = *reinterpret_cast<const float4*>(&bs[((size_t)b * NBn + mm) * KC + g * 4]);
            rx += v.x; ry += v.y; rz += v.z; rw += v.w;
            if (mm < mA) { ax += v.x; ay += v.y; az += v.z; aw += v.w; }   // uniform
            if (mm < mB) { bx += v.x; by += v.y; bz += v.z; bw += v.w; }   // uniform
        }
        PS[0][g * 4] = ax; PS[0][g * 4 + 1] = ay; PS[0][g * 4 + 2] = az; PS[0][g * 4 + 3] = aw;
        PS[1][g * 4] = bx; PS[1][g * 4 + 1] = by; PS[1][g * 4 + 2] = bz; PS[1][g * 4 + 3] = bw;
        Tt[g * 4] = rx; Tt[g * 4 + 1] = ry; Tt[g * 4 + 2] = rz; Tt[g * 4 + 3] = rw;
    }
    __syncthreads();   // S1

    int cj[8];
#pragma unroll
    for (int j = 0; j < 8; j++) cj[j] = cls[half][grp * 8 + j];

    {
        float cs[21];
#pragma unroll
        for (int k = 0; k < 21; k++) cs[k] = 0.f;
#pragma unroll
        for (int t = 0; t < 8; t++) {
            int k = cj[t];
#pragma unroll
            for (int kk = 0; kk < 21; kk++) cs[kk] += (kk == k) ? sT[t] : 0.f;
        }
#pragma unroll
        for (int kk = 0; kk < 21; kk++) WS[half][grp][kk * 64 + lane] = cs[kk];
    }
    __syncthreads();   // S2

    // cooperative exclusive prefix over 8 wave rows, both halves
    for (int i = threadIdx.x; i < 2 * KC; i += 1024) {
        int h = (i >= KC) ? 1 : 0;
        int j = i - h * KC;
        float run = PS[h][j];
#pragma unroll
        for (int g = 0; g < 8; g++) {
            float w = WS[h][g][j];
            WS[h][g][j] = run;
            run += w;
        }
    }
    __syncthreads();   // S3

    float Tc[21], msW[21];
#pragma unroll
    for (int k = 0; k < 21; k++) Tc[k] = Tt[k * 64 + lane];
#pragma unroll
    for (int k = 0; k < 21; k++) msW[k] = WS[half][grp][k * 64 + lane];

    int nvalid = Ln - base;                          // may be <=0 for masked tile
    if (nvalid > 64) nvalid = 64;
#pragma unroll
    for (int t = 0; t < 8; t++) {
        int i = grp * 8 + t;
        if (i < nvalid) {                            // wave-uniform
            int cis = __builtin_amdgcn_readfirstlane(cj[t]);
            const float2* grow = Gg + cis * 21;
            float sv = sT[t];
            float accA = (((cis != 0) ? 1.f : 0.f) - grow[cis].y) * sv;
            float accB = 0.f;
#pragma unroll
            for (int k = 0; k < 21; k++) {
                float2 w = grow[k];                  // wave-uniform s_load (K$)
                accA = fmaf(w.x, msW[k], accA);
                accB = fmaf(w.y, Tc[k], accB);
            }
#pragma unroll
            for (int j = 0; j < 8; j++)
                if (j < t) {
                    int cjs = __builtin_amdgcn_readfirstlane(cj[j]);
                    accA = fmaf(grow[cjs].x, sT[j], accA);
                }
            fused[((size_t)b * Ln + base + i) * Cn + lane] = accA + accB;
        }
    }
}

extern "C" void kernel_launch(void* const* d_in, const int* in_sizes, int n_in,
                              void* d_out, int out_size, void* d_ws, size_t ws_size,
                              hipStream_t stream) {
    const float* cls_pred = (const float*)d_in[0];
    const float* source = (const float*)d_in[1];
    const float* cls_r_prob = (const float*)d_in[2];

    float* fused = (float*)d_out;
    float* src_out = fused + (size_t)Bn * Ln * Cn;

    char* w = (char*)d_ws;
    int* cls_idx = (int*)w;                                    // 92416 B
    size_t off = ((size_t)Bn * Ln * 4 + 1023) & ~(size_t)1023;
    float* bs = (float*)(w + off);                             // 16*23*1344*4 B
    float2* Gg = (float2*)(w + off + (size_t)Bn * NBn * KC * 4);

    hipLaunchKernelGGL(kB, dim3(Bn * NPAIR), dim3(512), 0, stream,
                       cls_pred, source, cls_r_prob, cls_idx, src_out, bs, Gg);
    hipLaunchKernelGGL(kC, dim3(Bn * NPAIR), dim3(1024), 0, stream,
                       src_out, cls_idx, Gg, bs, fused);
}

// Round 19
// 28.731 us; speedup vs baseline: 38.0173x; 1.0578x over previous
//
#include <hip/hip_runtime.h>
#include <math.h>

#define Bn 16
#define Ln 1444      // 38*38
#define NCn 21
#define Cn 64
#define NBn 23       // 64-position tiles
#define KC 1344      // 21*64

// ---- Kernel B: R13 version (passing, measured ~6.3 us) --------------------
__global__ __launch_bounds__(256) void kB(const float* __restrict__ cls_pred,
                                          const float* __restrict__ source,
                                          const float* __restrict__ R,
                                          int* __restrict__ cls_idx,
                                          float* __restrict__ src_out,
                                          float* __restrict__ bs,
                                          float2* __restrict__ Gg) {
    int b = blockIdx.x & 15, m = blockIdx.x >> 4;
    int base = m * 64;
    int lane = threadIdx.x & 63, grp = threadIdx.x >> 6;
    __shared__ float sh[9536];
    __shared__ int cls[64];
    float (*tile)[65] = (float(*)[65])sh;
    float* clsP = sh + 4160;
    float* WS   = sh + 4160;

    if (blockIdx.x == 0) {
        for (int i = threadIdx.x; i < 441; i += 256) {
            int a = i / 21, k = i % 21;
            float rak = R[a * 21 + k], rka = R[k * 21 + a];
            Gg[i] = make_float2(rak - rka, rka);
        }
    }
#pragma unroll
    for (int cc = 0; cc < 16; cc++) {
        int c = grp * 16 + cc;
        float v = 0.f;
        if (base + lane < Ln) v = source[((size_t)b * Cn + c) * Ln + base + lane];
        tile[c][lane] = v;
    }
    {
        const float4* gp = reinterpret_cast<const float4*>(cls_pred + ((size_t)b * Ln + base) * 84);
        int lim4 = (Ln - base) * 21;
#pragma unroll
        for (int it = 0; it < 6; it++) {
            int f4 = threadIdx.x + it * 256;
            if (f4 < 1344) {
                float4 v = (f4 < lim4) ? gp[f4] : make_float4(0.f, 0.f, 0.f, 0.f);
                reinterpret_cast<float4*>(clsP)[f4] = v;
            }
        }
    }
    __syncthreads();   // S1

    {
        int p = threadIdx.x >> 2, a = threadIdx.x & 3;
        bool valid = (base + p < Ln);
        const float* q = clsP + p * 84 + a * 21;
        float x[21];
#pragma unroll
        for (int i = 0; i < 21; i++) x[i] = q[i];
        float mx = x[0];
#pragma unroll
        for (int i = 1; i < 21; i++) mx = fmaxf(mx, x[i]);
        float s = 0.f;
#pragma unroll
        for (int i = 0; i < 21; i++) { x[i] = expf(x[i] - mx); s += x[i]; }
        float best = -1.f; int bi = 0;
#pragma unroll
        for (int i = 0; i < 21; i++) {
            float sm = x[i] / s;                     // exact per-element division (matches ref)
            if (sm > best) { best = sm; bi = a * 21 + i; }
        }
#pragma unroll
        for (int d = 1; d <= 2; d <<= 1) {
            float ob = __shfl_xor(best, d);
            int oi = __shfl_xor(bi, d);
            if (ob > best || (ob == best && oi < bi)) { best = ob; bi = oi; }
        }
        if (a == 0) {
            if (valid) { int k = bi % 21; cls[p] = k; cls_idx[b * Ln + base + p] = k; }
            else cls[p] = 255;
        }
    }
    __syncthreads();   // S2

    float cs[21];
#pragma unroll
    for (int k = 0; k < 21; k++) cs[k] = 0.f;
#pragma unroll
    for (int jj = 0; jj < 16; jj++) {
        int j = grp * 16 + jj;
        float v = tile[lane][j];
        if (base + j < Ln) src_out[((size_t)b * Ln + base + j) * Cn + lane] = v;
        int k = cls[j];
#pragma unroll
        for (int kk = 0; kk < 21; kk++) cs[kk] += (kk == k) ? v : 0.f;
    }
#pragma unroll
    for (int kk = 0; kk < 21; kk++) WS[grp * KC + kk * 64 + lane] = cs[kk];
    __syncthreads();   // S3

    for (int i = threadIdx.x; i < KC; i += 256) {
        float v = WS[i] + WS[KC + i] + WS[2 * KC + i] + WS[3 * KC + i];
        bs[((size_t)b * NBn + m) * KC + i] = v;
    }
}

// ---- Kernel C: R13 + block-shared W2 (accB hoisted out of the hot loop) ---
// LDS: PS/W2 5.4K + Tt 5.4K + WS[8] 43K + cls 256B  (~54 KB)
__global__ __launch_bounds__(512, 2) void kC(const float* __restrict__ src,
                                             const int* __restrict__ cls_idx,
                                             const float2* __restrict__ Gg,
                                             const float* __restrict__ bs,
                                             float* __restrict__ fused) {
    int b = blockIdx.x & 15, m = blockIdx.x >> 4;
    int base = m * 64;
    int lane = threadIdx.x & 63, grp = threadIdx.x >> 6;   // 8 waves, 8 pos each
    __shared__ float PS[KC];       // prefix over tiles < m; later overlaid by W2
    __shared__ float Tt[KC];       // batch totals
    __shared__ float WS[8][KC];    // per-wave class sums -> exclusive prefix in-place
    __shared__ int cls[64];

    float sT[8];
#pragma unroll
    for (int t = 0; t < 8; t++) {
        int i = grp * 8 + t;
        sT[t] = (base + i < Ln) ? src[((size_t)b * Ln + base + i) * Cn + lane] : 0.f;
    }
    if (threadIdx.x < 64) {
        int k = 0;
        if (base + (int)threadIdx.x < Ln) k = cls_idx[b * Ln + base + threadIdx.x];
        cls[threadIdx.x] = k;
    }
    if (threadIdx.x < KC / 4) {
        int g = threadIdx.x;
        float rx = 0.f, ry = 0.f, rz = 0.f, rw = 0.f;
        float px = 0.f, py = 0.f, pz = 0.f, pw = 0.f;
#pragma unroll
        for (int mm = 0; mm < NBn; mm++) {
            float4 v = *reinterpret_cast<const float4*>(&bs[((size_t)b * NBn + mm) * KC + g * 4]);
            rx += v.x; ry += v.y; rz += v.z; rw += v.w;
            if (mm < m) { px += v.x; py += v.y; pz += v.z; pw += v.w; }  // uniform branch
        }
        PS[g * 4] = px; PS[g * 4 + 1] = py; PS[g * 4 + 2] = pz; PS[g * 4 + 3] = pw;
        Tt[g * 4] = rx; Tt[g * 4 + 1] = ry; Tt[g * 4 + 2] = rz; Tt[g * 4 + 3] = rw;
    }
    __syncthreads();   // S1: PS/Tt/cls ready

    int cj[8];
#pragma unroll
    for (int j = 0; j < 8; j++) cj[j] = cls[grp * 8 + j];

    {
        float cs[21];
#pragma unroll
        for (int k = 0; k < 21; k++) cs[k] = 0.f;
#pragma unroll
        for (int t = 0; t < 8; t++) {
            int k = cj[t];
#pragma unroll
            for (int kk = 0; kk < 21; kk++) cs[kk] += (kk == k) ? sT[t] : 0.f;
        }
#pragma unroll
        for (int kk = 0; kk < 21; kk++) WS[grp][kk * 64 + lane] = cs[kk];
    }
    __syncthreads();   // S2: WS rows complete

    // exclusive prefix over 8 wave rows, seeded with PS (PS dead afterwards)
    for (int i = threadIdx.x; i < KC; i += 512) {
        float run = PS[i];
#pragma unroll
        for (int g = 0; g < 8; g++) {
            float w = WS[g][i];
            WS[g][i] = run;
            run += w;
        }
    }
    __syncthreads();   // S3: WS = prefix; PS dead

    // msW to registers; cooperative W2[a][c] = sum_k Gy[a,k]*Tt[k,c] into PS region
    float msW[21];
#pragma unroll
    for (int k = 0; k < 21; k++) msW[k] = WS[grp][k * 64 + lane];
    for (int a = grp; a < 21; a += 8) {                // a wave-uniform
        const float2* grow = Gg + a * 21;
        float acc = 0.f;
#pragma unroll
        for (int k = 0; k < 21; k++)
            acc = fmaf(grow[k].y, Tt[k * 64 + lane], acc);   // same k-order as before
        PS[a * 64 + lane] = acc;                       // W2 row
    }
    __syncthreads();   // S4: W2 ready

    // hot loop: accB is ONE LDS read; accA split even/odd for ILP
    int nvalid = (Ln - base < 64) ? (Ln - base) : 64;
#pragma unroll
    for (int t = 0; t < 8; t++) {
        int i = grp * 8 + t;
        if (i < nvalid) {                              // wave-uniform
            int cis = __builtin_amdgcn_readfirstlane(cj[t]);
            const float2* grow = Gg + cis * 21;
            float sv = sT[t];
            float acc0 = (((cis != 0) ? 1.f : 0.f) - grow[cis].y) * sv;
            float acc1 = 0.f;
#pragma unroll
            for (int k = 0; k < 21; k += 2)
                acc0 = fmaf(grow[k].x, msW[k], acc0);
#pragma unroll
            for (int k = 1; k < 21; k += 2)
                acc1 = fmaf(grow[k].x, msW[k], acc1);
#pragma unroll
            for (int j = 0; j < 8; j++)                // triangular j < t
                if (j < t) {
                    int cjs = __builtin_amdgcn_readfirstlane(cj[j]);
                    acc1 = fmaf(grow[cjs].x, sT[j], acc1);
                }
            float accB = PS[cis * 64 + lane];          // W2[cis][lane], conflict-free
            fused[((size_t)b * Ln + base + i) * Cn + lane] = (acc0 + acc1) + accB;
        }
    }
}

extern "C" void kernel_launch(void* const* d_in, const int* in_sizes, int n_in,
                              void* d_out, int out_size, void* d_ws, size_t ws_size,
                              hipStream_t stream) {
    const float* cls_pred = (const float*)d_in[0];
    const float* source = (const float*)d_in[1];
    const float* cls_r_prob = (const float*)d_in[2];

    float* fused = (float*)d_out;
    float* src_out = fused + (size_t)Bn * Ln * Cn;

    char* w = (char*)d_ws;
    int* cls_idx = (int*)w;                                    // 92416 B
    size_t off = ((size_t)Bn * Ln * 4 + 1023) & ~(size_t)1023;
    float* bs = (float*)(w + off);                             // 16*23*1344*4 = 1978368 B
    float2* Gg = (float2*)(w + off + (size_t)Bn * NBn * KC * 4);

    hipLaunchKernelGGL(kB, dim3(Bn * NBn), dim3(256), 0, stream,
                       cls_pred, source, cls_r_prob, cls_idx, src_out, bs, Gg);
    hipLaunchKernelGGL(kC, dim3(Bn * NBn), dim3(512), 0, stream,
                       src_out, cls_idx, Gg, bs, fused);
}